// Round 1
// baseline (6025.866 us; speedup 1.0000x reference)
//
#include <hip/hip_runtime.h>

#define NN 100000
#define NE 1600000
#define ALPHA 0.2f

// ---------------------------------------------------------------------------
// Kernel 1: node transform  Q = nf@Wq + bq, V = nf@Wv + bv   (fp32 vector ALU)
// 256 threads: j = t&63 (output col), r0 = t>>6 (row quad). 16 rows per iter.
// ---------------------------------------------------------------------------
__global__ __launch_bounds__(256) void transform_kernel(
    const float* __restrict__ nf, const float* __restrict__ Wq, const float* __restrict__ bq,
    const float* __restrict__ Wv, const float* __restrict__ bv,
    float* __restrict__ q, float* __restrict__ v)
{
    __shared__ float sWq[64][64];
    __shared__ float sWv[64][64];
    __shared__ float sX[16][64];
    for (int i = threadIdx.x; i < 4096; i += 256) {
        sWq[i >> 6][i & 63] = Wq[i];
        sWv[i >> 6][i & 63] = Wv[i];
    }
    const int j  = threadIdx.x & 63;
    const int r0 = threadIdx.x >> 6;
    const float bqj = bq[j], bvj = bv[j];
    __syncthreads();

    const int ngroups = (NN + 15) >> 4;
    for (int g = blockIdx.x; g < ngroups; g += gridDim.x) {
        const int base = g << 4;
        #pragma unroll
        for (int i = 0; i < 4; i++) {
            int idx = threadIdx.x + i * 256;
            int row = base + (idx >> 6);
            sX[idx >> 6][idx & 63] = (row < NN) ? nf[(size_t)row * 64 + (idx & 63)] : 0.0f;
        }
        __syncthreads();

        float aq0 = bqj, aq1 = bqj, aq2 = bqj, aq3 = bqj;
        float av0 = bvj, av1 = bvj, av2 = bvj, av3 = bvj;
        #pragma unroll 8
        for (int k = 0; k < 64; k++) {
            float wq = sWq[k][j], wv = sWv[k][j];
            float x0 = sX[r0 * 4 + 0][k];
            float x1 = sX[r0 * 4 + 1][k];
            float x2 = sX[r0 * 4 + 2][k];
            float x3 = sX[r0 * 4 + 3][k];
            aq0 += x0 * wq; av0 += x0 * wv;
            aq1 += x1 * wq; av1 += x1 * wv;
            aq2 += x2 * wq; av2 += x2 * wv;
            aq3 += x3 * wq; av3 += x3 * wv;
        }
        const int row = base + r0 * 4;
        if (row + 3 < NN) {
            q[(size_t)(row + 0) * 64 + j] = aq0;  v[(size_t)(row + 0) * 64 + j] = av0;
            q[(size_t)(row + 1) * 64 + j] = aq1;  v[(size_t)(row + 1) * 64 + j] = av1;
            q[(size_t)(row + 2) * 64 + j] = aq2;  v[(size_t)(row + 2) * 64 + j] = av2;
            q[(size_t)(row + 3) * 64 + j] = aq3;  v[(size_t)(row + 3) * 64 + j] = av3;
        } else {
            float aqs[4] = {aq0, aq1, aq2, aq3};
            float avs[4] = {av0, av1, av2, av3};
            #pragma unroll
            for (int i = 0; i < 4; i++)
                if (row + i < NN) {
                    q[(size_t)(row + i) * 64 + j] = aqs[i];
                    v[(size_t)(row + i) * 64 + j] = avs[i];
                }
        }
        __syncthreads();
    }
}

// ---------------------------------------------------------------------------
// Kernel 2: edge pass. 4 threads per edge (one per head, 16 channels each).
// logit = sum_c leaky(q[tgt]+v[src]) * ak[c][h];  w = exp(logit)  (no segmax
// needed: softmax is shift-invariant, logits are O(10) so exp is safe in fp32)
// atomicAdd denom[tgt,h] += w;  atomicAdd pooled[tgt,h,c] += w * v[src,h,c]
// ---------------------------------------------------------------------------
__global__ __launch_bounds__(256) void edge_kernel(
    const float* __restrict__ q, const float* __restrict__ v,
    const float* __restrict__ ak,   // [16][4] row-major: ak[c*4+h]
    const int* __restrict__ esrc, const int* __restrict__ etgt,
    float* __restrict__ pooled, float* __restrict__ denom)
{
    __shared__ float sak[64];
    if (threadIdx.x < 64) sak[threadIdx.x] = ak[threadIdx.x];
    __syncthreads();

    const int gid = blockIdx.x * 256 + threadIdx.x;
    if (gid >= NE * 4) return;
    const int e = gid >> 2;
    const int h = gid & 3;
    const int t = etgt[e], s = esrc[e];

    const float4* qp = (const float4*)(q + (size_t)t * 64 + h * 16);
    const float4* vp = (const float4*)(v + (size_t)s * 64 + h * 16);

    float logit = 0.0f;
    float vb[16];
    #pragma unroll
    for (int i = 0; i < 4; i++) {
        float4 qf = qp[i];
        float4 vf = vp[i];
        float f;
        f = qf.x + vf.x; f = f > 0.0f ? f : ALPHA * f; logit += f * sak[(i * 4 + 0) * 4 + h];
        f = qf.y + vf.y; f = f > 0.0f ? f : ALPHA * f; logit += f * sak[(i * 4 + 1) * 4 + h];
        f = qf.z + vf.z; f = f > 0.0f ? f : ALPHA * f; logit += f * sak[(i * 4 + 2) * 4 + h];
        f = qf.w + vf.w; f = f > 0.0f ? f : ALPHA * f; logit += f * sak[(i * 4 + 3) * 4 + h];
        vb[i * 4 + 0] = vf.x; vb[i * 4 + 1] = vf.y;
        vb[i * 4 + 2] = vf.z; vb[i * 4 + 3] = vf.w;
    }
    const float w = __expf(logit);
    atomicAdd(&denom[(size_t)t * 4 + h], w);
    float* pb = pooled + (size_t)t * 64 + h * 16;
    #pragma unroll
    for (int c = 0; c < 16; c++)
        atomicAdd(&pb[c], w * vb[c]);
}

// ---------------------------------------------------------------------------
// Kernel 3: finalize. out = leaky_relu(pooled / max(denom,>0 else 1))
// ---------------------------------------------------------------------------
__global__ __launch_bounds__(256) void final_kernel(
    float* __restrict__ out, const float* __restrict__ denom)
{
    const int idx = blockIdx.x * 256 + threadIdx.x;
    if (idx >= NN * 64) return;
    const int n = idx >> 6;
    const int h = (idx >> 4) & 3;
    float den = denom[n * 4 + h];
    den = den > 0.0f ? den : 1.0f;
    float x = out[idx] / den;
    out[idx] = x > 0.0f ? x : ALPHA * x;
}

extern "C" void kernel_launch(void* const* d_in, const int* in_sizes, int n_in,
                              void* d_out, int out_size, void* d_ws, size_t ws_size,
                              hipStream_t stream) {
    const float* nf   = (const float*)d_in[0];
    const float* Wq   = (const float*)d_in[1];
    const float* bq   = (const float*)d_in[2];
    const float* Wv   = (const float*)d_in[3];
    const float* bv   = (const float*)d_in[4];
    const float* ak   = (const float*)d_in[5];
    const int*   esrc = (const int*)d_in[6];
    const int*   etgt = (const int*)d_in[7];
    float* out = (float*)d_out;

    float* q     = (float*)d_ws;               // NN*64 floats
    float* v     = q + (size_t)NN * 64;        // NN*64 floats
    float* denom = v + (size_t)NN * 64;        // NN*4 floats

    // zero accumulators (timed replays are not re-poisoned by harness)
    hipMemsetAsync(out,   0, (size_t)NN * 64 * sizeof(float), stream);
    hipMemsetAsync(denom, 0, (size_t)NN * 4  * sizeof(float), stream);

    transform_kernel<<<1024, 256, 0, stream>>>(nf, Wq, bq, Wv, bv, q, v);
    edge_kernel<<<(NE * 4 + 255) / 256, 256, 0, stream>>>(q, v, ak, esrc, etgt, out, denom);
    final_kernel<<<(NN * 64 + 255) / 256, 256, 0, stream>>>(out, denom);
}

// Round 2
// 674.391 us; speedup vs baseline: 8.9353x; 8.9353x over previous
//
#include <hip/hip_runtime.h>

#define NN 100000
#define NE 1600000
#define ALPHA 0.2f

// ---------------------------------------------------------------------------
// Kernel 1: node transform  Q = nf@Wq + bq, V = nf@Wv + bv   (fp32 vector ALU)
// ---------------------------------------------------------------------------
__global__ __launch_bounds__(256) void transform_kernel(
    const float* __restrict__ nf, const float* __restrict__ Wq, const float* __restrict__ bq,
    const float* __restrict__ Wv, const float* __restrict__ bv,
    float* __restrict__ q, float* __restrict__ v)
{
    __shared__ float sWq[64][64];
    __shared__ float sWv[64][64];
    __shared__ float sX[16][64];
    for (int i = threadIdx.x; i < 4096; i += 256) {
        sWq[i >> 6][i & 63] = Wq[i];
        sWv[i >> 6][i & 63] = Wv[i];
    }
    const int j  = threadIdx.x & 63;
    const int r0 = threadIdx.x >> 6;
    const float bqj = bq[j], bvj = bv[j];
    __syncthreads();

    const int ngroups = (NN + 15) >> 4;
    for (int g = blockIdx.x; g < ngroups; g += gridDim.x) {
        const int base = g << 4;
        #pragma unroll
        for (int i = 0; i < 4; i++) {
            int idx = threadIdx.x + i * 256;
            int row = base + (idx >> 6);
            sX[idx >> 6][idx & 63] = (row < NN) ? nf[(size_t)row * 64 + (idx & 63)] : 0.0f;
        }
        __syncthreads();

        float aq0 = bqj, aq1 = bqj, aq2 = bqj, aq3 = bqj;
        float av0 = bvj, av1 = bvj, av2 = bvj, av3 = bvj;
        #pragma unroll 8
        for (int k = 0; k < 64; k++) {
            float wq = sWq[k][j], wv = sWv[k][j];
            float x0 = sX[r0 * 4 + 0][k];
            float x1 = sX[r0 * 4 + 1][k];
            float x2 = sX[r0 * 4 + 2][k];
            float x3 = sX[r0 * 4 + 3][k];
            aq0 += x0 * wq; av0 += x0 * wv;
            aq1 += x1 * wq; av1 += x1 * wv;
            aq2 += x2 * wq; av2 += x2 * wv;
            aq3 += x3 * wq; av3 += x3 * wv;
        }
        const int row = base + r0 * 4;
        if (row + 3 < NN) {
            q[(size_t)(row + 0) * 64 + j] = aq0;  v[(size_t)(row + 0) * 64 + j] = av0;
            q[(size_t)(row + 1) * 64 + j] = aq1;  v[(size_t)(row + 1) * 64 + j] = av1;
            q[(size_t)(row + 2) * 64 + j] = aq2;  v[(size_t)(row + 2) * 64 + j] = av2;
            q[(size_t)(row + 3) * 64 + j] = aq3;  v[(size_t)(row + 3) * 64 + j] = av3;
        } else {
            float aqs[4] = {aq0, aq1, aq2, aq3};
            float avs[4] = {av0, av1, av2, av3};
            #pragma unroll
            for (int i = 0; i < 4; i++)
                if (row + i < NN) {
                    q[(size_t)(row + i) * 64 + j] = aqs[i];
                    v[(size_t)(row + i) * 64 + j] = avs[i];
                }
        }
        __syncthreads();
    }
}

// ---------------------------------------------------------------------------
// CSR build: histogram -> single-block scan -> scatter (src ids, CSR order)
// ---------------------------------------------------------------------------
__global__ __launch_bounds__(256) void hist_kernel(
    const int* __restrict__ etgt, int* __restrict__ cnt)
{
    int e = blockIdx.x * 256 + threadIdx.x;
    if (e < NE) atomicAdd(&cnt[etgt[e]], 1);
}

__global__ __launch_bounds__(1024) void scan_kernel(
    const int* __restrict__ cnt, int* __restrict__ offs, int* __restrict__ cursor)
{
    __shared__ int ssum[1024];
    const int tid = threadIdx.x;
    const int per = (NN + 1023) / 1024;       // 98
    const int base = tid * per;
    int s = 0;
    for (int i = 0; i < per; i++) {
        int idx = base + i;
        if (idx < NN) s += cnt[idx];
    }
    ssum[tid] = s;
    __syncthreads();
    int total = s;
    for (int off = 1; off < 1024; off <<= 1) {
        int t = (tid >= off) ? ssum[tid - off] : 0;
        __syncthreads();
        ssum[tid] += t;
        __syncthreads();
    }
    int run = ssum[tid] - total;              // exclusive prefix of this thread's chunk
    for (int i = 0; i < per; i++) {
        int idx = base + i;
        if (idx < NN) {
            offs[idx] = run;
            cursor[idx] = run;
            run += cnt[idx];
        }
    }
    if (tid == 1023) offs[NN] = run;
}

__global__ __launch_bounds__(256) void scatter_kernel(
    const int* __restrict__ esrc, const int* __restrict__ etgt,
    int* __restrict__ cursor, int* __restrict__ ssrc)
{
    int e = blockIdx.x * 256 + threadIdx.x;
    if (e < NE) {
        int t = etgt[e];
        int p = atomicAdd(&cursor[t], 1);
        ssrc[p] = esrc[e];
    }
}

// ---------------------------------------------------------------------------
// Gather kernel: one 64-lane wave per node. lane = output channel (h*16+c).
// Per incoming edge: coalesced 256B load of v[src], per-head logit via
// 16-lane shfl_xor reduce, w = exp(logit), accumulate wsum and w*v in regs.
// No atomics, output written exactly once.
// ---------------------------------------------------------------------------
__global__ __launch_bounds__(256) void gather_kernel(
    const float* __restrict__ q, const float* __restrict__ v,
    const float* __restrict__ ak,   // [16][4] row-major: ak[c*4+h]
    const int* __restrict__ offs, const int* __restrict__ ssrc,
    float* __restrict__ out)
{
    const int node = (blockIdx.x * 256 + threadIdx.x) >> 6;
    const int lane = threadIdx.x & 63;
    if (node >= NN) return;
    const int h = lane >> 4;
    const int c = lane & 15;
    const float akl = ak[c * 4 + h];
    const float qv  = q[(size_t)node * 64 + lane];
    const int start = offs[node];
    const int end   = offs[node + 1];

    float acc = 0.0f, wsum = 0.0f;

    int p = start;
    float vv_next = 0.0f;
    if (p < end) vv_next = v[(size_t)ssrc[p] * 64 + lane];
    while (p < end) {
        float vv = vv_next;
        int pn = p + 1;
        if (pn < end) vv_next = v[(size_t)ssrc[pn] * 64 + lane];
        float f = qv + vv;
        f = f > 0.0f ? f : ALPHA * f;
        float x = f * akl;
        x += __shfl_xor(x, 1);
        x += __shfl_xor(x, 2);
        x += __shfl_xor(x, 4);
        x += __shfl_xor(x, 8);
        float w = __expf(x);
        wsum += w;
        acc  += w * vv;
        p = pn;
    }
    if (wsum <= 0.0f) wsum = 1.0f;
    float r = acc / wsum;
    out[(size_t)node * 64 + lane] = r > 0.0f ? r : ALPHA * r;
}

extern "C" void kernel_launch(void* const* d_in, const int* in_sizes, int n_in,
                              void* d_out, int out_size, void* d_ws, size_t ws_size,
                              hipStream_t stream) {
    const float* nf   = (const float*)d_in[0];
    const float* Wq   = (const float*)d_in[1];
    const float* bq   = (const float*)d_in[2];
    const float* Wv   = (const float*)d_in[3];
    const float* bv   = (const float*)d_in[4];
    const float* ak   = (const float*)d_in[5];
    const int*   esrc = (const int*)d_in[6];
    const int*   etgt = (const int*)d_in[7];
    float* out = (float*)d_out;

    // workspace layout (bytes):
    //   q:      NN*64 f32   = 25.6 MB
    //   v:      NN*64 f32   = 25.6 MB
    //   cnt:    NN    i32   = 0.4 MB
    //   offs:   NN+1  i32   = 0.4 MB
    //   cursor: NN    i32   = 0.4 MB
    //   ssrc:   NE    i32   = 6.4 MB
    float* q      = (float*)d_ws;
    float* v      = q + (size_t)NN * 64;
    int*   cnt    = (int*)(v + (size_t)NN * 64);
    int*   offs   = cnt + NN;
    int*   cursor = offs + (NN + 1);
    int*   ssrc   = cursor + NN;

    hipMemsetAsync(cnt, 0, (size_t)NN * sizeof(int), stream);

    transform_kernel<<<1024, 256, 0, stream>>>(nf, Wq, bq, Wv, bv, q, v);
    hist_kernel<<<(NE + 255) / 256, 256, 0, stream>>>(etgt, cnt);
    scan_kernel<<<1, 1024, 0, stream>>>(cnt, offs, cursor);
    scatter_kernel<<<(NE + 255) / 256, 256, 0, stream>>>(esrc, etgt, cursor, ssrc);
    gather_kernel<<<(NN * 64 + 255) / 256, 256, 0, stream>>>(q, v, ak, offs, ssrc, out);
}

// Round 3
// 403.952 us; speedup vs baseline: 14.9173x; 1.6695x over previous
//
#include <hip/hip_runtime.h>

#define NN 100000
#define NE 1600000
#define ALPHA 0.2f

#define SCAN_CHUNK 1024
#define NBLK ((NN + SCAN_CHUNK - 1) / SCAN_CHUNK)   // 98

// ---------------------------------------------------------------------------
// Kernel 1: node transform  Q = nf@Wq + bq, V = nf@Wv + bv   (fp32 vector ALU)
// ---------------------------------------------------------------------------
__global__ __launch_bounds__(256) void transform_kernel(
    const float* __restrict__ nf, const float* __restrict__ Wq, const float* __restrict__ bq,
    const float* __restrict__ Wv, const float* __restrict__ bv,
    float* __restrict__ q, float* __restrict__ v)
{
    __shared__ float sWq[64][64];
    __shared__ float sWv[64][64];
    __shared__ float sX[16][64];
    for (int i = threadIdx.x; i < 4096; i += 256) {
        sWq[i >> 6][i & 63] = Wq[i];
        sWv[i >> 6][i & 63] = Wv[i];
    }
    const int j  = threadIdx.x & 63;
    const int r0 = threadIdx.x >> 6;
    const float bqj = bq[j], bvj = bv[j];
    __syncthreads();

    const int ngroups = (NN + 15) >> 4;
    for (int g = blockIdx.x; g < ngroups; g += gridDim.x) {
        const int base = g << 4;
        #pragma unroll
        for (int i = 0; i < 4; i++) {
            int idx = threadIdx.x + i * 256;
            int row = base + (idx >> 6);
            sX[idx >> 6][idx & 63] = (row < NN) ? nf[(size_t)row * 64 + (idx & 63)] : 0.0f;
        }
        __syncthreads();

        float aq0 = bqj, aq1 = bqj, aq2 = bqj, aq3 = bqj;
        float av0 = bvj, av1 = bvj, av2 = bvj, av3 = bvj;
        #pragma unroll 8
        for (int k = 0; k < 64; k++) {
            float wq = sWq[k][j], wv = sWv[k][j];
            float x0 = sX[r0 * 4 + 0][k];
            float x1 = sX[r0 * 4 + 1][k];
            float x2 = sX[r0 * 4 + 2][k];
            float x3 = sX[r0 * 4 + 3][k];
            aq0 += x0 * wq; av0 += x0 * wv;
            aq1 += x1 * wq; av1 += x1 * wv;
            aq2 += x2 * wq; av2 += x2 * wv;
            aq3 += x3 * wq; av3 += x3 * wv;
        }
        const int row = base + r0 * 4;
        if (row + 3 < NN) {
            q[(size_t)(row + 0) * 64 + j] = aq0;  v[(size_t)(row + 0) * 64 + j] = av0;
            q[(size_t)(row + 1) * 64 + j] = aq1;  v[(size_t)(row + 1) * 64 + j] = av1;
            q[(size_t)(row + 2) * 64 + j] = aq2;  v[(size_t)(row + 2) * 64 + j] = av2;
            q[(size_t)(row + 3) * 64 + j] = aq3;  v[(size_t)(row + 3) * 64 + j] = av3;
        } else {
            float aqs[4] = {aq0, aq1, aq2, aq3};
            float avs[4] = {av0, av1, av2, av3};
            #pragma unroll
            for (int i = 0; i < 4; i++)
                if (row + i < NN) {
                    q[(size_t)(row + i) * 64 + j] = aqs[i];
                    v[(size_t)(row + i) * 64 + j] = avs[i];
                }
        }
        __syncthreads();
    }
}

// ---------------------------------------------------------------------------
// CSR build: histogram -> 3-kernel two-level scan -> scatter
// ---------------------------------------------------------------------------
__global__ __launch_bounds__(256) void hist_kernel(
    const int* __restrict__ etgt, int* __restrict__ cnt)
{
    int e = blockIdx.x * 256 + threadIdx.x;
    if (e < NE) atomicAdd(&cnt[etgt[e]], 1);
}

// A: per-block chunk sums (98 blocks x 1024 elements)
__global__ __launch_bounds__(256) void scan_partial_kernel(
    const int* __restrict__ cnt, int* __restrict__ bsum)
{
    const int b = blockIdx.x;
    const int base = b * SCAN_CHUNK + threadIdx.x * 4;
    int s = 0;
    #pragma unroll
    for (int i = 0; i < 4; i++) {
        int idx = base + i;
        if (idx < NN) s += cnt[idx];
    }
    // wave reduce
    #pragma unroll
    for (int off = 1; off < 64; off <<= 1) s += __shfl_xor(s, off);
    __shared__ int ws[4];
    if ((threadIdx.x & 63) == 0) ws[threadIdx.x >> 6] = s;
    __syncthreads();
    if (threadIdx.x == 0) bsum[b] = ws[0] + ws[1] + ws[2] + ws[3];
}

// B: scan the 98 block sums in-place (exclusive); offs[NN] = NE
__global__ __launch_bounds__(128) void scan_bsums_kernel(
    int* __restrict__ bsum, int* __restrict__ offs)
{
    __shared__ int s[128];
    const int t = threadIdx.x;
    int val = (t < NBLK) ? bsum[t] : 0;
    s[t] = val;
    __syncthreads();
    for (int off = 1; off < 128; off <<= 1) {
        int tv = (t >= off) ? s[t - off] : 0;
        __syncthreads();
        s[t] += tv;
        __syncthreads();
    }
    if (t < NBLK) bsum[t] = s[t] - val;   // exclusive prefix
    if (t == 0)   offs[NN] = NE;
}

// C: final scan — write offs/cursor
__global__ __launch_bounds__(256) void scan_final_kernel(
    const int* __restrict__ cnt, const int* __restrict__ bsum,
    int* __restrict__ offs, int* __restrict__ cursor)
{
    const int b = blockIdx.x;
    const int base = b * SCAN_CHUNK + threadIdx.x * 4;
    int c0 = 0, c1 = 0, c2 = 0, c3 = 0;
    if (base + 0 < NN) c0 = cnt[base + 0];
    if (base + 1 < NN) c1 = cnt[base + 1];
    if (base + 2 < NN) c2 = cnt[base + 2];
    if (base + 3 < NN) c3 = cnt[base + 3];
    int tsum = c0 + c1 + c2 + c3;

    // wave-level exclusive scan of tsum
    const int lanex = threadIdx.x & 63;
    int incl = tsum;
    #pragma unroll
    for (int off = 1; off < 64; off <<= 1) {
        int t = __shfl_up(incl, off);
        if (lanex >= off) incl += t;
    }
    __shared__ int wsum[4];
    if (lanex == 63) wsum[threadIdx.x >> 6] = incl;
    __syncthreads();
    int wbase = 0;
    const int wid = threadIdx.x >> 6;
    for (int w = 0; w < 4; w++) if (w < wid) wbase += wsum[w];
    int run = bsum[b] + wbase + (incl - tsum);

    if (base + 0 < NN) { offs[base + 0] = run; cursor[base + 0] = run; run += c0; }
    if (base + 1 < NN) { offs[base + 1] = run; cursor[base + 1] = run; run += c1; }
    if (base + 2 < NN) { offs[base + 2] = run; cursor[base + 2] = run; run += c2; }
    if (base + 3 < NN) { offs[base + 3] = run; cursor[base + 3] = run; }
}

__global__ __launch_bounds__(256) void scatter_kernel(
    const int* __restrict__ esrc, const int* __restrict__ etgt,
    int* __restrict__ cursor, int* __restrict__ ssrc)
{
    int e = blockIdx.x * 256 + threadIdx.x;
    if (e < NE) {
        int t = etgt[e];
        int p = atomicAdd(&cursor[t], 1);
        ssrc[p] = esrc[e];
    }
}

// ---------------------------------------------------------------------------
// Gather kernel: one 64-lane wave per node. lane = output channel (h*16+c).
// 2-deep software pipeline on the v[src] gather.
// ---------------------------------------------------------------------------
__global__ __launch_bounds__(256) void gather_kernel(
    const float* __restrict__ q, const float* __restrict__ v,
    const float* __restrict__ ak,   // [16][4] row-major: ak[c*4+h]
    const int* __restrict__ offs, const int* __restrict__ ssrc,
    float* __restrict__ out)
{
    const int node = (blockIdx.x * 256 + threadIdx.x) >> 6;
    const int lane = threadIdx.x & 63;
    if (node >= NN) return;
    const int h = lane >> 4;
    const int c = lane & 15;
    const float akl = ak[c * 4 + h];
    const float qv  = q[(size_t)node * 64 + lane];
    const int start = offs[node];
    const int end   = offs[node + 1];

    float acc = 0.0f, wsum = 0.0f;

    float vv0 = 0.0f, vv1 = 0.0f;
    if (start     < end) vv0 = v[(size_t)ssrc[start]     * 64 + lane];
    if (start + 1 < end) vv1 = v[(size_t)ssrc[start + 1] * 64 + lane];

    for (int p = start; p < end; p++) {
        float vv = vv0;
        vv0 = vv1;
        if (p + 2 < end) vv1 = v[(size_t)ssrc[p + 2] * 64 + lane];
        float f = qv + vv;
        f = f > 0.0f ? f : ALPHA * f;
        float x = f * akl;
        x += __shfl_xor(x, 1);
        x += __shfl_xor(x, 2);
        x += __shfl_xor(x, 4);
        x += __shfl_xor(x, 8);
        float w = __expf(x);
        wsum += w;
        acc  += w * vv;
    }
    if (wsum <= 0.0f) wsum = 1.0f;
    float r = acc / wsum;
    out[(size_t)node * 64 + lane] = r > 0.0f ? r : ALPHA * r;
}

extern "C" void kernel_launch(void* const* d_in, const int* in_sizes, int n_in,
                              void* d_out, int out_size, void* d_ws, size_t ws_size,
                              hipStream_t stream) {
    const float* nf   = (const float*)d_in[0];
    const float* Wq   = (const float*)d_in[1];
    const float* bq   = (const float*)d_in[2];
    const float* Wv   = (const float*)d_in[3];
    const float* bv   = (const float*)d_in[4];
    const float* ak   = (const float*)d_in[5];
    const int*   esrc = (const int*)d_in[6];
    const int*   etgt = (const int*)d_in[7];
    float* out = (float*)d_out;

    // workspace layout:
    //   q:      NN*64 f32
    //   v:      NN*64 f32
    //   cnt:    NN    i32
    //   offs:   NN+1  i32
    //   cursor: NN    i32
    //   ssrc:   NE    i32
    //   bsum:   NBLK  i32
    float* q      = (float*)d_ws;
    float* v      = q + (size_t)NN * 64;
    int*   cnt    = (int*)(v + (size_t)NN * 64);
    int*   offs   = cnt + NN;
    int*   cursor = offs + (NN + 1);
    int*   ssrc   = cursor + NN;
    int*   bsum   = ssrc + NE;

    hipMemsetAsync(cnt, 0, (size_t)NN * sizeof(int), stream);

    transform_kernel<<<1024, 256, 0, stream>>>(nf, Wq, bq, Wv, bv, q, v);
    hist_kernel<<<(NE + 255) / 256, 256, 0, stream>>>(etgt, cnt);
    scan_partial_kernel<<<NBLK, 256, 0, stream>>>(cnt, bsum);
    scan_bsums_kernel<<<1, 128, 0, stream>>>(bsum, offs);
    scan_final_kernel<<<NBLK, 256, 0, stream>>>(cnt, bsum, offs, cursor);
    scatter_kernel<<<(NE + 255) / 256, 256, 0, stream>>>(esrc, etgt, cursor, ssrc);
    gather_kernel<<<(NN * 64 + 255) / 256, 256, 0, stream>>>(q, v, ak, offs, ssrc, out);
}